// Round 4
// baseline (174.085 us; speedup 1.0000x reference)
//
#include <hip/hip_runtime.h>
#include <cmath>

#define NLOC 1940
#define NPRI 8732
#define BATCH 16
#define KOBJ 10
#define NROWS 5   // max y-rows a 1024-pixel span can touch

// insert (v,i) into sorted-3 list (value desc, index asc — stable-argsort order)
__device__ __forceinline__ void ins3(float v, int i,
    float& a0, float& a1, float& a2, int& j0, int& j1, int& j2)
{
    if (v > a0 || (v == a0 && i < j0)) { a2=a1; j2=j1; a1=a0; j1=j0; a0=v; j0=i; }
    else if (v > a1 || (v == a1 && i < j1)) { a2=a1; j2=j1; a1=v; j1=i; }
    else if (v > a2 || (v == a2 && i < j2)) { a2=v; j2=i; }
}

// EXACT reference geometry chain: pixel index -> sampling coord (bitwise = ref)
__device__ __forceinline__ float ix_chain(int x, float shift, float wh) {
    const float xo = __fsub_rn(__fdiv_rn(__fadd_rn(__fmul_rn(2.0f, (float)x), 1.0f), 300.0f), 1.0f);
    const float u  = __fdiv_rn(__fsub_rn(xo, shift), wh);
    return __fmul_rn(__fsub_rn(__fmul_rn(__fadd_rn(u, 1.0f), 64.0f), 1.0f), 0.5f);
}

// ---------------------------------------------------------------------------
// dec_all: prep merged into the decoder (3 dispatches -> 2).
// Grid 16 x 48; block (r = L1-out px, s = sample). Every block:
//   A) top-3 depth reduction for its batch (redundant across the 48 blocks of
//      a batch; z_depth row is L2-resident, ~2 us total)
//   B) [r==0 && j==0 only, block-uniform] compacted STN params + exact integer
//      coverage intervals -> paramsF/paramsI/obnd (verbatim prep code)
//   C) 6-layer fused decoder, W0/W1 read DIRECTLY (transposed index, L2-hot)
// decoded is padded channel-last [s][4096 px][4] so stn can gather float4.
// ---------------------------------------------------------------------------
__global__ __launch_bounds__(256) void dec_all(
    const float* __restrict__ z_what, const float* __restrict__ z_where,
    const int* __restrict__ z_present, const float* __restrict__ z_depth,
    const float* __restrict__ W0, const float* __restrict__ b0v,
    const float* __restrict__ W1, const float* __restrict__ b1v,
    const float* __restrict__ W2, const float* __restrict__ b2v,
    const float* __restrict__ W3, const float* __restrict__ b3v,
    const float* __restrict__ W4, const float* __restrict__ b4v,
    const float* __restrict__ W5, const float* __restrict__ b5v,
    float* __restrict__ paramsF, int* __restrict__ paramsI, int* __restrict__ obnd,
    float* __restrict__ decoded)
{
    __shared__ float sv[768];
    __shared__ int   si[768];
    __shared__ int   sj_start[3], sj_bpl[3];
    __shared__ int   spres[10], sjj[10];
    __shared__ float szw[10][4];
    __shared__ float lpf[KOBJ][4];
    __shared__ int   lcnt;
    __shared__ __align__(16) float P[1024];
    __shared__ __align__(16) float Q[512];
    __shared__ __align__(16) float Zs[64];

    const int r  = blockIdx.x;                // 0..15: L1-out px
    const int s  = blockIdx.y;                // 0..47: sample
    const int t  = threadIdx.x;
    const int b  = s / 3;
    const int j  = s - 3 * b;
    const int y1 = r >> 2, x1 = r & 3;
    const int q0 = (y1 >> 1) * 2 + (x1 >> 1);
    const int p1 = (y1 & 1) * 2 + (x1 & 1);

    // ---- Phase A: top-3 locations by depth for batch b ----
    {
        float v0 = -INFINITY, v1 = -INFINITY, v2 = -INFINITY;
        int   i0 = NLOC, i1 = NLOC, i2 = NLOC;
        for (int i = t; i < NLOC; i += 256) {
            float v = z_depth[b * NLOC + i];
            ins3(v, i, v0, v1, v2, i0, i1, i2);
        }
        sv[t*3+0] = v0; sv[t*3+1] = v1; sv[t*3+2] = v2;
        si[t*3+0] = i0; si[t*3+1] = i1; si[t*3+2] = i2;
        __syncthreads();
        for (int st = 128; st > 0; st >>= 1) {
            if (t < st) {
                float a0 = sv[t*3], a1 = sv[t*3+1], a2 = sv[t*3+2];
                int   j0 = si[t*3], j1 = si[t*3+1], j2 = si[t*3+2];
                const int o = t + st;
                ins3(sv[o*3+0], si[o*3+0], a0, a1, a2, j0, j1, j2);
                ins3(sv[o*3+1], si[o*3+1], a0, a1, a2, j0, j1, j2);
                ins3(sv[o*3+2], si[o*3+2], a0, a1, a2, j0, j1, j2);
                sv[t*3] = a0; sv[t*3+1] = a1; sv[t*3+2] = a2;
                si[t*3] = j0; si[t*3+1] = j1; si[t*3+2] = j2;
            }
            __syncthreads();
        }
    }
    // si[0..2] = top-3 locations (stable order). Valid for all threads now.

    // ---- Phase B: params/obnd for stn (16 designated blocks; block-uniform) ----
    if (r == 0 && j == 0) {
        if (t < 3) {
            int L = si[t];
            int start, bpl;
            if (L < 1444)      { start = 4 * L;                 bpl = 4; }
            else if (L < 1805) { start = 5776 + 6 * (L - 1444); bpl = 6; }
            else if (L < 1905) { start = 7942 + 6 * (L - 1805); bpl = 6; }
            else if (L < 1930) { start = 8542 + 6 * (L - 1905); bpl = 6; }
            else if (L < 1939) { start = 8692 + 4 * (L - 1930); bpl = 4; }
            else               { start = 8728;                  bpl = 4; }
            sj_start[t] = start; sj_bpl[t] = bpl;
        }
        __syncthreads();
        if (t < 10) {   // parallel candidate loads (sum bpl >= 12 -> always 10 candidates)
            const int c0 = sj_bpl[0], c1 = sj_bpl[1];
            int jj, o;
            if (t < c0)           { jj = 0; o = t; }
            else if (t < c0 + c1) { jj = 1; o = t - c0; }
            else                  { jj = 2; o = t - c0 - c1; }
            const int p = sj_start[jj] + o;
            sjj[t]   = jj;
            spres[t] = z_present[b * NPRI + p];
            const float4 zw = *reinterpret_cast<const float4*>(z_where + (b * NPRI + p) * 4);
            szw[t][0] = zw.x; szw[t][1] = zw.y; szw[t][2] = zw.z; szw[t][3] = zw.w;
        }
        __syncthreads();
        if (t == 0) {
            int cnt = 0;
            for (int i = 0; i < 10; ++i) {
                if (spres[i] == 1) {
                    float p0 = __fadd_rn(szw[i][2], 1e-6f);
                    float p1v = __fadd_rn(szw[i][3], 1e-6f);
                    float p2 = __fsub_rn(__fmul_rn(2.0f, szw[i][0]), 1.0f);
                    float p3 = __fsub_rn(__fmul_rn(2.0f, szw[i][1]), 1.0f);
                    float* pf = paramsF + (b * KOBJ + cnt) * 4;
                    pf[0] = p0; pf[1] = p1v; pf[2] = p2; pf[3] = p3;
                    lpf[cnt][0] = p0; lpf[cnt][1] = p1v; lpf[cnt][2] = p2; lpf[cnt][3] = p3;
                    paramsI[b * 12 + 2 + cnt] = b * 3 + sjj[i];
                    cnt++;
                }
            }
            paramsI[b * 12] = cnt;
            lcnt = cnt;
        }
        __syncthreads();
        // exact integer coverage intervals: ty 0=xlo 1=xhi 2=ylo 3=yhi
        if (t < 4 * KOBJ) {
            const int k = t >> 2, ty = t & 3;
            if (k < lcnt) {
                const float wh = (ty < 2) ? lpf[k][0] : lpf[k][1];
                const float sh = (ty < 2) ? lpf[k][2] : lpf[k][3];
                int res;
                if ((ty & 1) == 0) {           // first index with chain > -1
                    int lo = 0, hi = 300;
                    while (lo < hi) { int m = (lo + hi) >> 1;
                        if (ix_chain(m, sh, wh) > -1.0f) hi = m; else lo = m + 1; }
                    res = lo;
                } else {                        // last index with chain < 64
                    int lo = -1, hi = 299;
                    while (lo < hi) { int m = (lo + hi + 1) >> 1;
                        if (ix_chain(m, sh, wh) < 64.0f) lo = m; else hi = m - 1; }
                    res = lo;
                }
                obnd[(b * KOBJ + k) * 4 + ty] = res;
            }
        }
        __syncthreads();
    }

    // ---- Phase C: fused decoder for sample s, location si[j] ----
    {
        const int L = si[j];
        if (t < 64) Zs[t] = z_what[(b * NLOC + L) * 64 + t];
    }
    __syncthreads();

    // ---- L0: o = t; W0 direct (elem c: W0[c*1024 + t*4 + q0]) ----
    {
        const float* w0 = W0 + (t << 2) + q0;
        float acc = b0v[t];
        #pragma unroll 8
        for (int c = 0; c < 64; ++c)
            acc = fmaf(Zs[c], w0[c << 10], acc);
        P[t] = fmaxf(acc, 0.f);
    }
    __syncthreads();

    // ---- L1: o = t&127, c halved by h; W1 direct (elem c: W1[c*512 + o*4 + p1]) ----
    {
        const int o = t & 127, h = t >> 7;
        const float* w1 = W1 + (o << 2) + p1;
        float acc = (h == 0) ? b1v[o] : 0.f;
        const int cb = h << 7;
        #pragma unroll 8
        for (int c = 0; c < 128; ++c)
            acc = fmaf(P[cb + c], w1[(cb + c) << 9], acc);
        if (h == 1) P[256 + o] = acc;
        __syncthreads();
        if (h == 0)
            Q[o] = fmaxf(acc + P[256 + o], 0.f);
    }
    __syncthreads();

    // ---- L2: f = t ----
    {
        const float* w2 = W2 + t;
        float acc = b2v[t >> 2];
        #pragma unroll 8
        for (int ci = 0; ci < 128; ++ci)
            acc = fmaf(Q[ci], w2[ci << 8], acc);
        P[t] = fmaxf(acc, 0.f);
    }
    __syncthreads();

    // ---- L3: px = t&15, coa = t>>4 handles {coa, coa+16} ----
    {
        const int px = t & 15, coa = t >> 4;
        const int ly = px >> 2, lx = px & 3;
        const int par = (ly >> 1) * 2 + (lx >> 1);
        const int wp  = (ly & 1) * 2 + (lx & 1);
        const float* w3 = W3 + coa * 4 + wp;
        float a0 = b3v[coa];
        float a1 = b3v[coa + 16];
        #pragma unroll 8
        for (int ci = 0; ci < 64; ++ci) {
            float xs = P[(ci << 2) + par];
            a0 = fmaf(xs, w3[ci << 7], a0);
            a1 = fmaf(xs, w3[(ci << 7) + 64], a1);
        }
        Q[(coa << 4) + px] = fmaxf(a0, 0.f);
        Q[((coa + 16) << 4) + px] = fmaxf(a1, 0.f);
    }
    __syncthreads();

    // ---- L4: px = t&63, co = t>>6 + {0,4,8,12} ----
    {
        const int px = t & 63, co0 = t >> 6;
        const int ly = px >> 3, lx = px & 7;
        const int par = (ly >> 1) * 4 + (lx >> 1);
        const int wp  = (ly & 1) * 2 + (lx & 1);
        const float* w4 = W4 + co0 * 4 + wp;
        float acc[4];
        #pragma unroll
        for (int k = 0; k < 4; ++k) acc[k] = b4v[co0 + 4 * k];
        #pragma unroll 4
        for (int ci = 0; ci < 32; ++ci) {
            float xs = Q[(ci << 4) + par];
            #pragma unroll
            for (int k = 0; k < 4; ++k)
                acc[k] = fmaf(xs, w4[(ci << 6) + k * 16], acc[k]);
        }
        #pragma unroll
        for (int k = 0; k < 4; ++k)
            P[((co0 + 4 * k) << 6) + px] = fmaxf(acc[k], 0.f);
    }
    __syncthreads();

    // ---- L5: px = t, sigmoid -> global padded channel-last (float4) ----
    {
        const int px = t;
        const int ly = px >> 4, lx = px & 15;
        const int par = (ly >> 1) * 8 + (lx >> 1);
        const int wp  = (ly & 1) * 2 + (lx & 1);
        const int gy = y1 * 16 + ly, gx = x1 * 16 + lx;
        const float* w5 = W5 + wp;
        float acc[3];
        #pragma unroll
        for (int c = 0; c < 3; ++c) acc[c] = b5v[c];
        #pragma unroll 4
        for (int ci = 0; ci < 16; ++ci) {
            float xs = P[(ci << 6) + par];
            #pragma unroll
            for (int c = 0; c < 3; ++c)
                acc[c] = fmaf(xs, w5[ci * 12 + c * 4], acc[c]);
        }
        const int pbase = (gy * 64 + gx) * 4;
        float4 v;
        v.x = 1.0f / (1.0f + expf(-acc[0]));
        v.y = 1.0f / (1.0f + expf(-acc[1]));
        v.z = 1.0f / (1.0f + expf(-acc[2]));
        v.w = 0.0f;
        *reinterpret_cast<float4*>(decoded + s * 16384 + pbase) = v;
    }
}

// ---------------------------------------------------------------------------
// STN + first-nonzero composite. 1024 pixels per block (grid 88 x 16).
// Per-pixel math bitwise-identical to reference.
// ---------------------------------------------------------------------------
__global__ __launch_bounds__(256) void stn_kernel(
    const float* __restrict__ decoded, const float* __restrict__ paramsF,
    const int* __restrict__ paramsI, const int* __restrict__ obnd,
    float* __restrict__ out)
{
    const int b = blockIdx.y;
    const int pix0 = blockIdx.x * 1024;
    const int yfirst = pix0 / 300;
    __shared__ float sp[KOBJ][4];
    __shared__ int   ssamp[KOBJ];
    __shared__ int   s_xlo[KOBJ], s_xhi[KOBJ], s_ylo[KOBJ], s_yhi[KOBJ];
    __shared__ int   scnt;
    __shared__ float s_wy0[KOBJ][NROWS], s_wy1[KOBJ][NROWS];
    __shared__ int   s_rb0[KOBJ][NROWS], s_rb1[KOBJ][NROWS];
    __shared__ unsigned char s_cov[KOBJ][NROWS];
    __shared__ unsigned char s_vy[KOBJ][NROWS];
    __shared__ int s_list[KOBJ];
    __shared__ int s_lc;
    const int tid = threadIdx.x;

    if (tid == 0) scnt = paramsI[b * 12];
    if (tid < KOBJ) {
        #pragma unroll
        for (int c = 0; c < 4; ++c) sp[tid][c] = paramsF[(b * KOBJ + tid) * 4 + c];
        ssamp[tid] = paramsI[b * 12 + 2 + tid];
        const int4 bd = *reinterpret_cast<const int4*>(obnd + (b * KOBJ + tid) * 4);
        s_xlo[tid] = bd.x; s_xhi[tid] = bd.y; s_ylo[tid] = bd.z; s_yhi[tid] = bd.w;
    }
    __syncthreads();

    if (tid < NROWS * scnt) {
        const int k = tid / NROWS, sel = tid - k * NROWS;
        int yy = yfirst + sel; if (yy > 299) yy = 299;
        const bool cov = (yy >= s_ylo[k]) && (yy <= s_yhi[k]);
        s_cov[k][sel] = cov ? 1 : 0;
        if (cov) {
            const float iy = ix_chain(yy, sp[k][3], sp[k][1]);
            const float iy0f = floorf(iy);
            const float iy1f = __fadd_rn(iy0f, 1.0f);
            const float wy1  = __fsub_rn(iy, iy0f);
            s_wy1[k][sel] = wy1;
            s_wy0[k][sel] = __fsub_rn(1.0f, wy1);
            const bool vy0 = (iy0f >= 0.0f) && (iy0f < 64.0f);
            const bool vy1 = (iy1f >= 0.0f) && (iy1f < 64.0f);
            s_vy[k][sel] = (unsigned char)((vy0 ? 1 : 0) | (vy1 ? 2 : 0));
            s_rb0[k][sel] = ((int)fminf(fmaxf(iy0f, 0.0f), 63.0f)) * 64;
            s_rb1[k][sel] = ((int)fminf(fmaxf(iy1f, 0.0f), 63.0f)) * 64;
        }
    }
    __syncthreads();
    if (tid == 0) {
        int lc = 0;
        for (int k = 0; k < scnt; ++k) {
            unsigned char any = 0;
            #pragma unroll
            for (int r = 0; r < NROWS; ++r) any |= s_cov[k][r];
            if (any) s_list[lc++] = k;
        }
        s_lc = lc;
    }
    __syncthreads();

    const int lc = s_lc;
    #pragma unroll
    for (int q = 0; q < 4; ++q) {
        const int pix = pix0 + q * 256 + tid;
        if (pix < 90000) {
            const int y = pix / 300;
            const int x = pix - y * 300;
            const int rs = y - yfirst;
            float o0 = 0.0f, o1 = 0.0f, o2 = 0.0f;
            bool d0 = false, d1 = false, d2 = false;
            for (int m = 0; m < lc; ++m) {
                const int k = s_list[m];
                if (!s_cov[k][rs]) continue;
                if (x < s_xlo[k] || x > s_xhi[k]) continue;   // exact integer coverage cull

                const float ix = ix_chain(x, sp[k][2], sp[k][0]);
                const float ix0f = floorf(ix);
                const float ix1f = __fadd_rn(ix0f, 1.0f);
                const float wx1 = __fsub_rn(ix, ix0f);
                const float wx0 = __fsub_rn(1.0f, wx1);
                const bool vx0 = (ix0f >= 0.0f) && (ix0f < 64.0f);
                const bool vx1 = (ix1f >= 0.0f) && (ix1f < 64.0f);
                const int x0 = (int)fminf(fmaxf(ix0f, 0.0f), 63.0f);
                const int x1 = (int)fminf(fmaxf(ix1f, 0.0f), 63.0f);

                const float wy0 = s_wy0[k][rs], wy1 = s_wy1[k][rs];
                const int rb0 = s_rb0[k][rs], rb1 = s_rb1[k][rs];
                const unsigned char vy = s_vy[k][rs];
                const bool m00 = (vy & 1) && vx0, m01 = (vy & 1) && vx1;
                const bool m10 = (vy & 2) && vx0, m11 = (vy & 2) && vx1;
                const float* img = decoded + ssamp[k] * 16384;

                const float4 z4 = make_float4(0.f, 0.f, 0.f, 0.f);
                const float4 g00 = m00 ? *reinterpret_cast<const float4*>(img + ((rb0 + x0) << 2)) : z4;
                const float4 g01 = m01 ? *reinterpret_cast<const float4*>(img + ((rb0 + x1) << 2)) : z4;
                const float4 g10 = m10 ? *reinterpret_cast<const float4*>(img + ((rb1 + x0) << 2)) : z4;
                const float4 g11 = m11 ? *reinterpret_cast<const float4*>(img + ((rb1 + x1) << 2)) : z4;

                if (!d0) {
                    float val = g00.x * wy0 * wx0 + g01.x * wy0 * wx1 + g10.x * wy1 * wx0 + g11.x * wy1 * wx1;
                    if (val != 0.0f) { o0 = val; d0 = true; }
                }
                if (!d1) {
                    float val = g00.y * wy0 * wx0 + g01.y * wy0 * wx1 + g10.y * wy1 * wx0 + g11.y * wy1 * wx1;
                    if (val != 0.0f) { o1 = val; d1 = true; }
                }
                if (!d2) {
                    float val = g00.z * wy0 * wx0 + g01.z * wy0 * wx1 + g10.z * wy1 * wx0 + g11.z * wy1 * wx1;
                    if (val != 0.0f) { o2 = val; d2 = true; }
                }
                if (d0 && d1 && d2) break;
            }
            const int ob = b * 270000 + pix;
            out[ob] = o0;
            out[ob + 90000] = o1;
            out[ob + 180000] = o2;
        }
    }
}

extern "C" void kernel_launch(void* const* d_in, const int* in_sizes, int n_in,
                              void* d_out, int out_size, void* d_ws, size_t ws_size,
                              hipStream_t stream)
{
    const float* z_what    = (const float*)d_in[0];
    const float* z_where   = (const float*)d_in[1];
    const int*   z_present = (const int*)d_in[2];
    const float* z_depth   = (const float*)d_in[3];
    const float* W0 = (const float*)d_in[4];   const float* b0 = (const float*)d_in[5];
    const float* W1 = (const float*)d_in[6];   const float* b1 = (const float*)d_in[7];
    const float* W2 = (const float*)d_in[8];   const float* b2 = (const float*)d_in[9];
    const float* W3 = (const float*)d_in[10];  const float* b3 = (const float*)d_in[11];
    const float* W4 = (const float*)d_in[12];  const float* b4 = (const float*)d_in[13];
    const float* W5 = (const float*)d_in[14];  const float* b5 = (const float*)d_in[15];

    float* ws = (float*)d_ws;
    float* paramsF  = ws + 16384;               // 640 floats
    int*   paramsI  = (int*)(ws + 17408);       // 192 ints
    int*   obnd     = (int*)(ws + 17664);       // 640 ints (16-aligned)
    float* decoded  = ws + 32768;               // 48*16384 floats, padded channel-last (~3.1 MB)
    float* outp     = (float*)d_out;

    hipLaunchKernelGGL(dec_all, dim3(16, 48), dim3(256), 0, stream,
                       z_what, z_where, z_present, z_depth,
                       W0, b0, W1, b1, W2, b2, W3, b3, W4, b4, W5, b5,
                       paramsF, paramsI, obnd, decoded);
    hipLaunchKernelGGL(stn_kernel, dim3(88, BATCH), dim3(256), 0, stream,
                       decoded, paramsF, paramsI, obnd, outp);
}

// Round 5
// 150.110 us; speedup vs baseline: 1.1597x; 1.1597x over previous
//
#include <hip/hip_runtime.h>
#include <cmath>

#define NLOC 1940
#define NPRI 8732
#define BATCH 16
#define KOBJ 10
#define NROWS 5   // max y-rows a 1024-pixel span can touch

// insert (v,i) into sorted-3 list (value desc, index asc — stable-argsort order)
__device__ __forceinline__ void ins3(float v, int i,
    float& a0, float& a1, float& a2, int& j0, int& j1, int& j2)
{
    if (v > a0 || (v == a0 && i < j0)) { a2=a1; j2=j1; a1=a0; j1=j0; a0=v; j0=i; }
    else if (v > a1 || (v == a1 && i < j1)) { a2=a1; j2=j1; a1=v; j1=i; }
    else if (v > a2 || (v == a2 && i < j2)) { a2=v; j2=i; }
}

// EXACT reference geometry chain: pixel index -> sampling coord (bitwise = ref)
__device__ __forceinline__ float ix_chain(int x, float shift, float wh) {
    const float xo = __fsub_rn(__fdiv_rn(__fadd_rn(__fmul_rn(2.0f, (float)x), 1.0f), 300.0f), 1.0f);
    const float u  = __fdiv_rn(__fsub_rn(xo, shift), wh);
    return __fmul_rn(__fsub_rn(__fmul_rn(__fadd_rn(u, 1.0f), 64.0f), 1.0f), 0.5f);
}

// ---------------------------------------------------------------------------
// prep_kernel: blocks 0..767 repack W0/W1 into Wr[pos][c][o] (coalesced decoder
// reads — R4 proved direct reads cost ~45 us); blocks 768..783: per-batch top-3
// locations, compacted STN params, exact integer coverage intervals.
// ---------------------------------------------------------------------------
__global__ __launch_bounds__(256) void prep_kernel(
    const float* __restrict__ W0, const float* __restrict__ W1, float* __restrict__ Wr,
    const float* __restrict__ z_what, const float* __restrict__ z_where,
    const int* __restrict__ z_present, const float* __restrict__ z_depth,
    float* __restrict__ gathered, float* __restrict__ paramsF, int* __restrict__ paramsI,
    int* __restrict__ obnd)
{
    __shared__ float sv[768];
    __shared__ int   si[768];
    __shared__ int   locs3[3];
    __shared__ int   sj_start[3], sj_bpl[3];
    __shared__ int   spres[10], sjj[10];
    __shared__ float szw[10][4];
    __shared__ float lpf[KOBJ][4];
    __shared__ int   lcnt;
    const int tid = threadIdx.x;

    if (blockIdx.x < 768) {
        const int idx = blockIdx.x * 256 + tid;
        if (idx < 65536) {
            int q = idx >> 14, rem = idx & 16383, c = rem >> 8, o = rem & 255;
            Wr[idx] = W0[(((c << 8) | o) << 2) + q];
        } else {
            int i2 = idx - 65536;
            int q = i2 >> 15, rem = i2 & 32767, c = rem >> 7, o = rem & 127;
            Wr[idx] = W1[(((c << 7) | o) << 2) + q];
        }
        return;
    }

    const int b = blockIdx.x - 768;
    float v0 = -INFINITY, v1 = -INFINITY, v2 = -INFINITY;
    int   i0 = NLOC, i1 = NLOC, i2 = NLOC;
    for (int i = tid; i < NLOC; i += 256) {
        float v = z_depth[b * NLOC + i];
        ins3(v, i, v0, v1, v2, i0, i1, i2);
    }
    sv[tid*3+0] = v0; sv[tid*3+1] = v1; sv[tid*3+2] = v2;
    si[tid*3+0] = i0; si[tid*3+1] = i1; si[tid*3+2] = i2;
    __syncthreads();
    for (int s = 128; s > 0; s >>= 1) {
        if (tid < s) {
            float a0 = sv[tid*3], a1 = sv[tid*3+1], a2 = sv[tid*3+2];
            int   j0 = si[tid*3], j1 = si[tid*3+1], j2 = si[tid*3+2];
            const int o = tid + s;
            ins3(sv[o*3+0], si[o*3+0], a0, a1, a2, j0, j1, j2);
            ins3(sv[o*3+1], si[o*3+1], a0, a1, a2, j0, j1, j2);
            ins3(sv[o*3+2], si[o*3+2], a0, a1, a2, j0, j1, j2);
            sv[tid*3] = a0; sv[tid*3+1] = a1; sv[tid*3+2] = a2;
            si[tid*3] = j0; si[tid*3+1] = j1; si[tid*3+2] = j2;
        }
        __syncthreads();
    }

    if (tid < 3) {
        int L = si[tid];
        locs3[tid] = L;
        int start, bpl;
        if (L < 1444)      { start = 4 * L;                 bpl = 4; }
        else if (L < 1805) { start = 5776 + 6 * (L - 1444); bpl = 6; }
        else if (L < 1905) { start = 7942 + 6 * (L - 1805); bpl = 6; }
        else if (L < 1930) { start = 8542 + 6 * (L - 1905); bpl = 6; }
        else if (L < 1939) { start = 8692 + 4 * (L - 1930); bpl = 4; }
        else               { start = 8728;                  bpl = 4; }
        sj_start[tid] = start; sj_bpl[tid] = bpl;
    }
    __syncthreads();
    if (tid < 10) {   // parallel candidate loads (sum bpl >= 12 -> always 10 candidates)
        const int b0 = sj_bpl[0], b1 = sj_bpl[1];
        int j, o;
        if (tid < b0)           { j = 0; o = tid; }
        else if (tid < b0 + b1) { j = 1; o = tid - b0; }
        else                    { j = 2; o = tid - b0 - b1; }
        const int p = sj_start[j] + o;
        sjj[tid]   = j;
        spres[tid] = z_present[b * NPRI + p];
        const float4 zw = *reinterpret_cast<const float4*>(z_where + (b * NPRI + p) * 4);
        szw[tid][0] = zw.x; szw[tid][1] = zw.y; szw[tid][2] = zw.z; szw[tid][3] = zw.w;
    }
    __syncthreads();
    if (tid == 0) {
        int cnt = 0;
        for (int i = 0; i < 10; ++i) {
            if (spres[i] == 1) {
                float p0 = __fadd_rn(szw[i][2], 1e-6f);
                float p1 = __fadd_rn(szw[i][3], 1e-6f);
                float p2 = __fsub_rn(__fmul_rn(2.0f, szw[i][0]), 1.0f);
                float p3 = __fsub_rn(__fmul_rn(2.0f, szw[i][1]), 1.0f);
                float* pf = paramsF + (b * KOBJ + cnt) * 4;
                pf[0] = p0; pf[1] = p1; pf[2] = p2; pf[3] = p3;
                lpf[cnt][0] = p0; lpf[cnt][1] = p1; lpf[cnt][2] = p2; lpf[cnt][3] = p3;
                paramsI[b * 12 + 2 + cnt] = b * 3 + sjj[i];
                cnt++;
            }
        }
        paramsI[b * 12] = cnt;
        lcnt = cnt;
    }
    __syncthreads();
    // exact integer coverage intervals: ty 0=xlo 1=xhi 2=ylo 3=yhi
    if (tid < 4 * KOBJ) {
        const int k = tid >> 2, ty = tid & 3;
        if (k < lcnt) {
            const float wh = (ty < 2) ? lpf[k][0] : lpf[k][1];
            const float sh = (ty < 2) ? lpf[k][2] : lpf[k][3];
            int res;
            if ((ty & 1) == 0) {           // first index with chain > -1
                int lo = 0, hi = 300;
                while (lo < hi) { int m = (lo + hi) >> 1;
                    if (ix_chain(m, sh, wh) > -1.0f) hi = m; else lo = m + 1; }
                res = lo;
            } else {                        // last index with chain < 64
                int lo = -1, hi = 299;
                while (lo < hi) { int m = (lo + hi + 1) >> 1;
                    if (ix_chain(m, sh, wh) < 64.0f) lo = m; else hi = m - 1; }
                res = lo;
            }
            obnd[(b * KOBJ + k) * 4 + ty] = res;
        }
    }
    if (tid < 192) {
        int j = tid >> 6, c = tid & 63;
        gathered[(b * 3 + j) * 64 + c] = z_what[(b * NLOC + locs3[j]) * 64 + c];
    }
}

// ---------------------------------------------------------------------------
// Fused 6-layer decoder, 1 sample/block, grid 16x48. LATENCY FIX (R5): weights
// are staged into statically-indexed register arrays in 32/64-wide batches
// before the FMA chain -> 32+ independent loads in flight per wave (was 8 via
// unroll-8). FMA order per accumulator unchanged -> bitwise-identical output.
// ---------------------------------------------------------------------------
__global__ __launch_bounds__(256) void dec_fused(
    const float* __restrict__ gathered, const float* __restrict__ Wr,
    const float* __restrict__ b0v, const float* __restrict__ b1v,
    const float* __restrict__ W2, const float* __restrict__ b2v,
    const float* __restrict__ W3, const float* __restrict__ b3v,
    const float* __restrict__ W4, const float* __restrict__ b4v,
    const float* __restrict__ W5, const float* __restrict__ b5v,
    float* __restrict__ decoded)
{
    __shared__ __align__(16) float P[1024];
    __shared__ __align__(16) float Q[512];
    __shared__ __align__(16) float Zs[64];
    const int r  = blockIdx.x;                // 0..15: L1-out px
    const int s  = blockIdx.y;                // 0..47: sample
    const int t  = threadIdx.x;
    const int y1 = r >> 2, x1 = r & 3;
    const int q0 = (y1 >> 1) * 2 + (x1 >> 1);
    const int p1 = (y1 & 1) * 2 + (x1 & 1);

    if (t < 64) Zs[t] = gathered[s * 64 + t];
    __syncthreads();

    // ---- L0: o = t; K=64, register-staged weights ----
    {
        const float* w0 = Wr + q0 * 16384 + t;
        float w[64];
        #pragma unroll
        for (int c = 0; c < 64; ++c) w[c] = w0[c << 8];
        float acc = b0v[t];
        #pragma unroll
        for (int c = 0; c < 64; ++c) acc = fmaf(Zs[c], w[c], acc);
        P[t] = fmaxf(acc, 0.f);
    }
    __syncthreads();

    // ---- L1: o = t&127, c halved by h; K=128/thread, staged in 32-batches ----
    {
        const int o = t & 127, h = t >> 7;
        const float* w1 = Wr + 65536 + p1 * 32768 + o;
        float acc = (h == 0) ? b1v[o] : 0.f;
        const int cb = h << 7;
        #pragma unroll
        for (int cc = 0; cc < 128; cc += 32) {
            float w[32];
            #pragma unroll
            for (int c = 0; c < 32; ++c) w[c] = w1[(cb + cc + c) << 7];
            #pragma unroll
            for (int c = 0; c < 32; ++c) acc = fmaf(P[cb + cc + c], w[c], acc);
        }
        if (h == 1) P[256 + o] = acc;
        __syncthreads();
        if (h == 0)
            Q[o] = fmaxf(acc + P[256 + o], 0.f);
    }
    __syncthreads();

    // ---- L2: f = t; K=128, staged in 32-batches ----
    {
        const float* w2 = W2 + t;
        float acc = b2v[t >> 2];
        #pragma unroll
        for (int cc = 0; cc < 128; cc += 32) {
            float w[32];
            #pragma unroll
            for (int ci = 0; ci < 32; ++ci) w[ci] = w2[(cc + ci) << 8];
            #pragma unroll
            for (int ci = 0; ci < 32; ++ci) acc = fmaf(Q[cc + ci], w[ci], acc);
        }
        P[t] = fmaxf(acc, 0.f);
    }
    __syncthreads();

    // ---- L3: px = t&15, coa = t>>4 handles {coa, coa+16}; staged 2x32 ----
    {
        const int px = t & 15, coa = t >> 4;
        const int ly = px >> 2, lx = px & 3;
        const int par = (ly >> 1) * 2 + (lx >> 1);
        const int wp  = (ly & 1) * 2 + (lx & 1);
        const float* w3 = W3 + coa * 4 + wp;
        float a0 = b3v[coa];
        float a1 = b3v[coa + 16];
        #pragma unroll
        for (int cc = 0; cc < 64; cc += 32) {
            float wa[32], wb[32];
            #pragma unroll
            for (int ci = 0; ci < 32; ++ci) {
                wa[ci] = w3[(cc + ci) << 7];
                wb[ci] = w3[((cc + ci) << 7) + 64];
            }
            #pragma unroll
            for (int ci = 0; ci < 32; ++ci) {
                float xs = P[((cc + ci) << 2) + par];
                a0 = fmaf(xs, wa[ci], a0);
                a1 = fmaf(xs, wb[ci], a1);
            }
        }
        Q[(coa << 4) + px] = fmaxf(a0, 0.f);
        Q[((coa + 16) << 4) + px] = fmaxf(a1, 0.f);
    }
    __syncthreads();

    // ---- L4: px = t&63, co = t>>6 + {0,4,8,12}; 4 chains give ILP already ----
    {
        const int px = t & 63, co0 = t >> 6;
        const int ly = px >> 3, lx = px & 7;
        const int par = (ly >> 1) * 4 + (lx >> 1);
        const int wp  = (ly & 1) * 2 + (lx & 1);
        const float* w4 = W4 + co0 * 4 + wp;
        float acc[4];
        #pragma unroll
        for (int k = 0; k < 4; ++k) acc[k] = b4v[co0 + 4 * k];
        #pragma unroll 8
        for (int ci = 0; ci < 32; ++ci) {
            float xs = Q[(ci << 4) + par];
            #pragma unroll
            for (int k = 0; k < 4; ++k)
                acc[k] = fmaf(xs, w4[(ci << 6) + k * 16], acc[k]);
        }
        #pragma unroll
        for (int k = 0; k < 4; ++k)
            P[((co0 + 4 * k) << 6) + px] = fmaxf(acc[k], 0.f);
    }
    __syncthreads();

    // ---- L5: px = t, sigmoid -> global padded channel-last (float4) ----
    {
        const int px = t;
        const int ly = px >> 4, lx = px & 15;
        const int par = (ly >> 1) * 8 + (lx >> 1);
        const int wp  = (ly & 1) * 2 + (lx & 1);
        const int gy = y1 * 16 + ly, gx = x1 * 16 + lx;
        const float* w5 = W5 + wp;
        float acc[3];
        #pragma unroll
        for (int c = 0; c < 3; ++c) acc[c] = b5v[c];
        #pragma unroll 8
        for (int ci = 0; ci < 16; ++ci) {
            float xs = P[(ci << 6) + par];
            #pragma unroll
            for (int c = 0; c < 3; ++c)
                acc[c] = fmaf(xs, w5[ci * 12 + c * 4], acc[c]);
        }
        const int pbase = (gy * 64 + gx) * 4;
        float4 v;
        v.x = 1.0f / (1.0f + expf(-acc[0]));
        v.y = 1.0f / (1.0f + expf(-acc[1]));
        v.z = 1.0f / (1.0f + expf(-acc[2]));
        v.w = 0.0f;
        *reinterpret_cast<float4*>(decoded + s * 16384 + pbase) = v;
    }
}

// evaluate one object's contribution at (x, rs): sets pass + 3 channel vals.
// Verbatim arithmetic from the reference chain.
#define EVAL_OBJ(KIDX, PASS, V0, V1, V2)                                          \
    {                                                                             \
        const int k = (KIDX);                                                     \
        if (s_cov[k][rs] && x >= s_xlo[k] && x <= s_xhi[k]) {                     \
            PASS = true;                                                          \
            const float ix = ix_chain(x, sp[k][2], sp[k][0]);                     \
            const float ix0f = floorf(ix);                                        \
            const float ix1f = __fadd_rn(ix0f, 1.0f);                             \
            const float wx1 = __fsub_rn(ix, ix0f);                                \
            const float wx0 = __fsub_rn(1.0f, wx1);                               \
            const bool vx0 = (ix0f >= 0.0f) && (ix0f < 64.0f);                    \
            const bool vx1 = (ix1f >= 0.0f) && (ix1f < 64.0f);                    \
            const int x0 = (int)fminf(fmaxf(ix0f, 0.0f), 63.0f);                  \
            const int x1 = (int)fminf(fmaxf(ix1f, 0.0f), 63.0f);                  \
            const float wy0 = s_wy0[k][rs], wy1 = s_wy1[k][rs];                   \
            const int rb0 = s_rb0[k][rs], rb1 = s_rb1[k][rs];                     \
            const unsigned char vy = s_vy[k][rs];                                 \
            const bool m00 = (vy & 1) && vx0, m01 = (vy & 1) && vx1;              \
            const bool m10 = (vy & 2) && vx0, m11 = (vy & 2) && vx1;              \
            const float* img = decoded + ssamp[k] * 16384;                        \
            const float4 z4 = make_float4(0.f, 0.f, 0.f, 0.f);                    \
            const float4 g00 = m00 ? *reinterpret_cast<const float4*>(img + ((rb0 + x0) << 2)) : z4; \
            const float4 g01 = m01 ? *reinterpret_cast<const float4*>(img + ((rb0 + x1) << 2)) : z4; \
            const float4 g10 = m10 ? *reinterpret_cast<const float4*>(img + ((rb1 + x0) << 2)) : z4; \
            const float4 g11 = m11 ? *reinterpret_cast<const float4*>(img + ((rb1 + x1) << 2)) : z4; \
            V0 = g00.x * wy0 * wx0 + g01.x * wy0 * wx1 + g10.x * wy1 * wx0 + g11.x * wy1 * wx1; \
            V1 = g00.y * wy0 * wx0 + g01.y * wy0 * wx1 + g10.y * wy1 * wx0 + g11.y * wy1 * wx1; \
            V2 = g00.z * wy0 * wx0 + g01.z * wy0 * wx1 + g10.z * wy1 * wx0 + g11.z * wy1 * wx1; \
        }                                                                         \
    }

// ---------------------------------------------------------------------------
// STN + first-nonzero composite. 1024 px/block (grid 88x16). LATENCY FIX (R5):
// objects evaluated in PAIRS — both candidates' divide+gather chains issue
// before either is consumed; consumption stays strictly in object order with
// per-channel first-nonzero semantics -> identical output, half the serial
// latency rounds on overlapping-object pixels.
// ---------------------------------------------------------------------------
__global__ __launch_bounds__(256) void stn_kernel(
    const float* __restrict__ decoded, const float* __restrict__ paramsF,
    const int* __restrict__ paramsI, const int* __restrict__ obnd,
    float* __restrict__ out)
{
    const int b = blockIdx.y;
    const int pix0 = blockIdx.x * 1024;
    const int yfirst = pix0 / 300;
    __shared__ float sp[KOBJ][4];
    __shared__ int   ssamp[KOBJ];
    __shared__ int   s_xlo[KOBJ], s_xhi[KOBJ], s_ylo[KOBJ], s_yhi[KOBJ];
    __shared__ int   scnt;
    __shared__ float s_wy0[KOBJ][NROWS], s_wy1[KOBJ][NROWS];
    __shared__ int   s_rb0[KOBJ][NROWS], s_rb1[KOBJ][NROWS];
    __shared__ unsigned char s_cov[KOBJ][NROWS];
    __shared__ unsigned char s_vy[KOBJ][NROWS];
    __shared__ int s_list[KOBJ];
    __shared__ int s_lc;
    const int tid = threadIdx.x;

    if (tid == 0) scnt = paramsI[b * 12];
    if (tid < KOBJ) {
        #pragma unroll
        for (int c = 0; c < 4; ++c) sp[tid][c] = paramsF[(b * KOBJ + tid) * 4 + c];
        ssamp[tid] = paramsI[b * 12 + 2 + tid];
        const int4 bd = *reinterpret_cast<const int4*>(obnd + (b * KOBJ + tid) * 4);
        s_xlo[tid] = bd.x; s_xhi[tid] = bd.y; s_ylo[tid] = bd.z; s_yhi[tid] = bd.w;
    }
    __syncthreads();

    if (tid < NROWS * scnt) {
        const int k = tid / NROWS, sel = tid - k * NROWS;
        int yy = yfirst + sel; if (yy > 299) yy = 299;
        const bool cov = (yy >= s_ylo[k]) && (yy <= s_yhi[k]);
        s_cov[k][sel] = cov ? 1 : 0;
        if (cov) {
            const float iy = ix_chain(yy, sp[k][3], sp[k][1]);
            const float iy0f = floorf(iy);
            const float iy1f = __fadd_rn(iy0f, 1.0f);
            const float wy1  = __fsub_rn(iy, iy0f);
            s_wy1[k][sel] = wy1;
            s_wy0[k][sel] = __fsub_rn(1.0f, wy1);
            const bool vy0 = (iy0f >= 0.0f) && (iy0f < 64.0f);
            const bool vy1 = (iy1f >= 0.0f) && (iy1f < 64.0f);
            s_vy[k][sel] = (unsigned char)((vy0 ? 1 : 0) | (vy1 ? 2 : 0));
            s_rb0[k][sel] = ((int)fminf(fmaxf(iy0f, 0.0f), 63.0f)) * 64;
            s_rb1[k][sel] = ((int)fminf(fmaxf(iy1f, 0.0f), 63.0f)) * 64;
        }
    }
    __syncthreads();
    if (tid == 0) {
        int lc = 0;
        for (int k = 0; k < scnt; ++k) {
            unsigned char any = 0;
            #pragma unroll
            for (int r = 0; r < NROWS; ++r) any |= s_cov[k][r];
            if (any) s_list[lc++] = k;
        }
        s_lc = lc;
    }
    __syncthreads();

    const int lc = s_lc;
    for (int q = 0; q < 4; ++q) {
        const int pix = pix0 + q * 256 + tid;
        if (pix < 90000) {
            const int y = pix / 300;
            const int x = pix - y * 300;
            const int rs = y - yfirst;
            float o0 = 0.0f, o1 = 0.0f, o2 = 0.0f;
            bool d0 = false, d1 = false, d2 = false;
            for (int mb = 0; mb < lc; mb += 2) {
                float a0v = 0.f, a1v = 0.f, a2v = 0.f; bool pa = false;
                float c0v = 0.f, c1v = 0.f, c2v = 0.f; bool pc = false;
                EVAL_OBJ(s_list[mb], pa, a0v, a1v, a2v);
                if (mb + 1 < lc) EVAL_OBJ(s_list[mb + 1], pc, c0v, c1v, c2v);
                if (pa) {
                    if (!d0 && a0v != 0.0f) { o0 = a0v; d0 = true; }
                    if (!d1 && a1v != 0.0f) { o1 = a1v; d1 = true; }
                    if (!d2 && a2v != 0.0f) { o2 = a2v; d2 = true; }
                }
                if (pc) {
                    if (!d0 && c0v != 0.0f) { o0 = c0v; d0 = true; }
                    if (!d1 && c1v != 0.0f) { o1 = c1v; d1 = true; }
                    if (!d2 && c2v != 0.0f) { o2 = c2v; d2 = true; }
                }
                if (d0 && d1 && d2) break;
            }
            const int ob = b * 270000 + pix;
            out[ob] = o0;
            out[ob + 90000] = o1;
            out[ob + 180000] = o2;
        }
    }
}

extern "C" void kernel_launch(void* const* d_in, const int* in_sizes, int n_in,
                              void* d_out, int out_size, void* d_ws, size_t ws_size,
                              hipStream_t stream)
{
    const float* z_what    = (const float*)d_in[0];
    const float* z_where   = (const float*)d_in[1];
    const int*   z_present = (const int*)d_in[2];
    const float* z_depth   = (const float*)d_in[3];
    const float* W0 = (const float*)d_in[4];   const float* b0 = (const float*)d_in[5];
    const float* W1 = (const float*)d_in[6];   const float* b1 = (const float*)d_in[7];
    const float* W2 = (const float*)d_in[8];   const float* b2 = (const float*)d_in[9];
    const float* W3 = (const float*)d_in[10];  const float* b3 = (const float*)d_in[11];
    const float* W4 = (const float*)d_in[12];  const float* b4 = (const float*)d_in[13];
    const float* W5 = (const float*)d_in[14];  const float* b5 = (const float*)d_in[15];

    float* ws = (float*)d_ws;
    float* gathered = ws;                       // 48*64 floats
    float* paramsF  = ws + 16384;               // 640 floats
    int*   paramsI  = (int*)(ws + 17408);       // 192 ints
    int*   obnd     = (int*)(ws + 17664);       // 640 ints (16-aligned)
    float* decoded  = ws + 32768;               // 48*16384 floats, padded channel-last (~3.1 MB)
    float* Wr       = (float*)d_out;            // scratch until stn overwrites
    float* outp     = (float*)d_out;

    hipLaunchKernelGGL(prep_kernel, dim3(784), dim3(256), 0, stream,
                       W0, W1, Wr, z_what, z_where, z_present, z_depth,
                       gathered, paramsF, paramsI, obnd);
    hipLaunchKernelGGL(dec_fused, dim3(16, 48), dim3(256), 0, stream,
                       gathered, Wr, b0, b1, W2, b2, W3, b3, W4, b4, W5, b5, decoded);
    hipLaunchKernelGGL(stn_kernel, dim3(88, BATCH), dim3(256), 0, stream,
                       decoded, paramsF, paramsI, obnd, outp);
}